// Round 4
// baseline (2532.857 us; speedup 1.0000x reference)
//
#include <hip/hip_runtime.h>

// ---------------- static config ----------------
constexpr int MTOK = 200704;      // B*H*W = 64*56*56
constexpr int CD   = 192;
constexpr int NHEAD = 6;
constexpr int HD   = 32;
constexpr int NT   = 49;          // tokens per window
constexpr float QSCALE = 0.17677669529663687f;  // 32^-0.5

using bf16x8 = __attribute__((ext_vector_type(8))) short;
using f32x4  = __attribute__((ext_vector_type(4))) float;

__device__ __forceinline__ unsigned short f2b(float f) {
  unsigned int u = __float_as_uint(f);
  u += 0x7fffu + ((u >> 16) & 1u);        // RNE to bf16
  return (unsigned short)(u >> 16);
}
__device__ __forceinline__ float b2f(unsigned short s) {
  return __uint_as_float(((unsigned int)s) << 16);
}

// ---- weights: in [K,N] f32 -> out [N,K] bf16 (tiny, ~442K elems total)
__global__ void wtrans_kernel(const float* __restrict__ in,
                              unsigned short* __restrict__ out, int K, int N) {
  int idx = blockIdx.x * 256 + threadIdx.x;
  if (idx >= K * N) return;
  int k = idx / N, n = idx - k * N;
  out[(size_t)n * K + k] = f2b(in[idx]);
}

// ---- LayerNorm over C=192; 4 rows/block, one wave per row
__global__ __launch_bounds__(256) void ln_kernel(const float* __restrict__ x,
    const float* __restrict__ w, const float* __restrict__ b,
    unsigned short* __restrict__ out) {
  int row  = blockIdx.x * 4 + (threadIdx.x >> 6);
  int lane = threadIdx.x & 63;
  const float* xr = x + (size_t)row * CD;
  float v0 = xr[lane], v1 = xr[lane + 64], v2 = xr[lane + 128];
  float s = v0 + v1 + v2;
  for (int o = 32; o; o >>= 1) s += __shfl_xor(s, o);
  float mu = s * (1.f / 192.f);
  float d0 = v0 - mu, d1 = v1 - mu, d2 = v2 - mu;
  float vv = d0 * d0 + d1 * d1 + d2 * d2;
  for (int o = 32; o; o >>= 1) vv += __shfl_xor(vv, o);
  float rstd = rsqrtf(vv * (1.f / 192.f) + 1e-5f);
  unsigned short* orow = out + (size_t)row * CD;
  orow[lane]       = f2b(d0 * rstd * w[lane]       + b[lane]);
  orow[lane + 64]  = f2b(d1 * rstd * w[lane + 64]  + b[lane + 64]);
  orow[lane + 128] = f2b(d2 * rstd * w[lane + 128] + b[lane + 128]);
}

// ---- bf16 MFMA GEMM: C[M,N] = A[M,K] * WT[N,K]^T (+bias, epilogue variants)
// EPI: 0 = bias -> bf16 ; 1 = bias + resid(f32) -> f32 ;
//      2 = bias + exact GELU -> bf16 ; 3 = bias, += into f32 out
template<int EPI>
__global__ __launch_bounds__(256) void gemm_kernel(
    const unsigned short* __restrict__ A,   // [M,K] bf16
    const unsigned short* __restrict__ WT,  // [N,K] bf16
    const float* __restrict__ bias,         // [N]
    void* __restrict__ outp,
    const float* __restrict__ resid,        // [M,N] for EPI==1
    int N, int K) {
  // LDS layout [kgroup][row][8] keeps ds_read_b128 fragments aligned + conflict-light
  __shared__ __align__(16) unsigned short As[4][64][8];
  __shared__ __align__(16) unsigned short Bs[4][64][8];
  const int m0 = blockIdx.x * 64, n0 = blockIdx.y * 64;
  const int t = threadIdx.x;
  const int wave = t >> 6, lane = t & 63;
  const int lrow = lane & 15, lkg = lane >> 4;
  const int srow = t >> 2, skg = t & 3;   // staging: 16B per thread, coalesced
  const unsigned short* Ab = A  + (size_t)(m0 + srow) * K + skg * 8;
  const unsigned short* Bb = WT + (size_t)(n0 + srow) * K + skg * 8;
  f32x4 acc[4] = {};
  for (int k0 = 0; k0 < K; k0 += 32) {
    __syncthreads();
    *reinterpret_cast<int4*>(&As[skg][srow][0]) = *reinterpret_cast<const int4*>(Ab + k0);
    *reinterpret_cast<int4*>(&Bs[skg][srow][0]) = *reinterpret_cast<const int4*>(Bb + k0);
    __syncthreads();
    // A-frag: lane holds A[m = l&15][k = (l>>4)*8 + j]
    bf16x8 a = *reinterpret_cast<const bf16x8*>(&As[lkg][wave * 16 + lrow][0]);
#pragma unroll
    for (int nt = 0; nt < 4; ++nt) {
      // B-frag: lane holds B[k = (l>>4)*8 + j][n = l&15]
      bf16x8 bf = *reinterpret_cast<const bf16x8*>(&Bs[lkg][nt * 16 + lrow][0]);
      acc[nt] = __builtin_amdgcn_mfma_f32_16x16x32_bf16(a, bf, acc[nt], 0, 0, 0);
    }
  }
  // C/D: row = (l>>4)*4 + r, col = l&15
#pragma unroll
  for (int nt = 0; nt < 4; ++nt) {
    int n = n0 + nt * 16 + lrow;
    float bv = bias[n];
#pragma unroll
    for (int r = 0; r < 4; ++r) {
      int m = m0 + wave * 16 + lkg * 4 + r;
      float val = acc[nt][r] + bv;
      size_t oi = (size_t)m * N + n;
      if constexpr (EPI == 0) {
        ((unsigned short*)outp)[oi] = f2b(val);
      } else if constexpr (EPI == 1) {
        ((float*)outp)[oi] = val + resid[oi];
      } else if constexpr (EPI == 2) {
        val = 0.5f * val * (1.f + erff(val * 0.70710678118654752f));
        ((unsigned short*)outp)[oi] = f2b(val);
      } else {
        ((float*)outp)[oi] += val;
      }
    }
  }
}

// ---- windowed attention: one wave per (window, head)
__global__ __launch_bounds__(64) void attn_kernel(
    const unsigned short* __restrict__ qkv,  // [M, 576] bf16 (3,NH,HD packing)
    const float* __restrict__ rpb,           // [169, 6]
    unsigned short* __restrict__ o) {        // [M, 192] bf16, natural token order
  int h   = blockIdx.x % NHEAD;
  int win = blockIdx.x / NHEAD;    // b*64 + w
  int b = win >> 6, w = win & 63;
  int wr = w >> 3, wc = w & 7;
  int lane = threadIdx.x;
  __shared__ float qs[NT][33], ks[NT][33], vsh[NT][33], ps[NT][50];
  __shared__ int toks[NT], regs[NT];
  if (lane < NT) {
    int ii = lane / 7, jj = lane - ii * 7;
    int hs = wr * 7 + ii, wsd = wc * 7 + jj;           // shifted-image coords
    toks[lane] = b * 3136 + ((hs + 3) % 56) * 56 + ((wsd + 3) % 56); // unshift
    int rh = hs < 49 ? 0 : (hs < 53 ? 1 : 2);          // shift-mask region id
    int rw = wsd < 49 ? 0 : (wsd < 53 ? 1 : 2);
    regs[lane] = rh * 3 + rw;
  }
  __syncthreads();
  for (int idx = lane; idx < NT * HD; idx += 64) {
    int i = idx >> 5, d = idx & 31;
    size_t base = (size_t)toks[i] * 576 + h * 32 + d;
    qs[i][d]  = b2f(qkv[base])       * QSCALE;
    ks[i][d]  = b2f(qkv[base + 192]);
    vsh[i][d] = b2f(qkv[base + 384]);
  }
  __syncthreads();
  int lh = lane / 7, lw = lane - lh * 7;
  int myreg = (lane < NT) ? regs[lane] : 0;
  for (int i = 0; i < NT; ++i) {
    float s = -1e30f;
    if (lane < NT) {
      float a = 0.f;
#pragma unroll
      for (int d = 0; d < HD; ++d) a += qs[i][d] * ks[lane][d];
      int ih = i / 7, iw = i - ih * 7;
      a += rpb[((ih - lh + 6) * 13 + (iw - lw + 6)) * 6 + h];
      if (regs[i] != myreg) a -= 100.f;
      s = a;
    }
    float mx = s;
    for (int off = 32; off; off >>= 1) mx = fmaxf(mx, __shfl_xor(mx, off));
    float e = (lane < NT) ? __expf(s - mx) : 0.f;
    float sum = e;
    for (int off = 32; off; off >>= 1) sum += __shfl_xor(sum, off);
    if (lane < NT) ps[i][lane] = e / sum;
  }
  __syncthreads();
  for (int i = 0; i < NT; ++i) {
    if (lane < HD) {
      float a = 0.f;
#pragma unroll
      for (int j = 0; j < NT; ++j) a += ps[i][j] * vsh[j][lane];
      o[(size_t)toks[i] * CD + h * 32 + lane] = f2b(a);
    }
  }
}

extern "C" void kernel_launch(void* const* d_in, const int* in_sizes, int n_in,
                              void* d_out, int out_size, void* d_ws, size_t ws_size,
                              hipStream_t stream) {
  const float* x      = (const float*)d_in[0];
  const float* n1w    = (const float*)d_in[1];
  const float* n1b    = (const float*)d_in[2];
  const float* qkv_w  = (const float*)d_in[3];
  const float* qkv_b  = (const float*)d_in[4];
  const float* rpb    = (const float*)d_in[5];
  const float* proj_w = (const float*)d_in[6];
  const float* proj_b = (const float*)d_in[7];
  const float* n2w    = (const float*)d_in[8];
  const float* n2b    = (const float*)d_in[9];
  const float* fc1_w  = (const float*)d_in[10];
  const float* fc1_b  = (const float*)d_in[11];
  const float* fc2_w  = (const float*)d_in[12];
  const float* fc2_b  = (const float*)d_in[13];
  float* out = (float*)d_out;
  char* ws = (char*)d_ws;

  // workspace layout (bytes); hid aliases qkv+o (576+192=768 cols exactly)
  constexpr size_t SZ_HN  = (size_t)MTOK * CD  * 2;   // 77,070,336
  constexpr size_t SZ_QKV = (size_t)MTOK * 576 * 2;   // 231,211,008
  constexpr size_t OFF_QKV = SZ_HN;
  constexpr size_t OFF_O   = OFF_QKV + SZ_QKV;
  constexpr size_t OFF_WT  = OFF_O + SZ_HN;           // ~385.4 MB
  unsigned short* hnorm = (unsigned short*)(ws);            // LN1 out; reused for LN2
  unsigned short* qkvb  = (unsigned short*)(ws + OFF_QKV);
  unsigned short* obuf  = (unsigned short*)(ws + OFF_O);
  unsigned short* hid   = (unsigned short*)(ws + OFF_QKV);  // [M,768] aliases qkv+o
  unsigned short* qkv_wT  = (unsigned short*)(ws + OFF_WT); // [576,192]
  unsigned short* proj_wT = qkv_wT + 576 * 192;             // [192,192]
  unsigned short* fc1_wT  = proj_wT + 192 * 192;            // [768,192]
  unsigned short* fc2_wT  = fc1_wT + 768 * 192;             // [192,768]

  wtrans_kernel<<<(192 * 576 + 255) / 256, 256, 0, stream>>>(qkv_w, qkv_wT, 192, 576);
  wtrans_kernel<<<(192 * 192 + 255) / 256, 256, 0, stream>>>(proj_w, proj_wT, 192, 192);
  wtrans_kernel<<<(192 * 768 + 255) / 256, 256, 0, stream>>>(fc1_w, fc1_wT, 192, 768);
  wtrans_kernel<<<(768 * 192 + 255) / 256, 256, 0, stream>>>(fc2_w, fc2_wT, 768, 192);

  ln_kernel<<<MTOK / 4, 256, 0, stream>>>(x, n1w, n1b, hnorm);
  gemm_kernel<0><<<dim3(MTOK / 64, 9), 256, 0, stream>>>(hnorm, qkv_wT, qkv_b, qkvb, nullptr, 576, 192);
  attn_kernel<<<64 * 64 * NHEAD, 64, 0, stream>>>(qkvb, rpb, obuf);
  gemm_kernel<1><<<dim3(MTOK / 64, 3), 256, 0, stream>>>(obuf, proj_wT, proj_b, out, x, 192, 192);
  ln_kernel<<<MTOK / 4, 256, 0, stream>>>(out, n2w, n2b, hnorm);
  gemm_kernel<2><<<dim3(MTOK / 64, 12), 256, 0, stream>>>(hnorm, fc1_wT, fc1_b, hid, nullptr, 768, 192);
  gemm_kernel<3><<<dim3(MTOK / 64, 3), 256, 0, stream>>>(hid, fc2_wT, fc2_b, out, nullptr, 192, 768);
}

// Round 5
// 1266.634 us; speedup vs baseline: 1.9997x; 1.9997x over previous
//
#include <hip/hip_runtime.h>

// ---------------- static config ----------------
constexpr int MTOK = 200704;      // B*H*W = 64*56*56
constexpr int CD   = 192;
constexpr int NHEAD = 6;
constexpr int HD   = 32;
constexpr int NT   = 49;          // tokens per window
constexpr float QSCALE = 0.17677669529663687f;  // 32^-0.5

using bf16x8 = __attribute__((ext_vector_type(8))) short;
using bf16x4 = __attribute__((ext_vector_type(4))) short;
using f32x4  = __attribute__((ext_vector_type(4))) float;

__device__ __forceinline__ unsigned short f2b(float f) {
  unsigned int u = __float_as_uint(f);
  u += 0x7fffu + ((u >> 16) & 1u);        // RNE to bf16
  return (unsigned short)(u >> 16);
}
__device__ __forceinline__ float b2f(unsigned short s) {
  return __uint_as_float(((unsigned int)s) << 16);
}

// ---- weights: in [K,N] f32 -> out [N,K] bf16 (tiny, ~442K elems total)
__global__ void wtrans_kernel(const float* __restrict__ in,
                              unsigned short* __restrict__ out, int K, int N) {
  int idx = blockIdx.x * 256 + threadIdx.x;
  if (idx >= K * N) return;
  int k = idx / N, n = idx - k * N;
  out[(size_t)n * K + k] = f2b(in[idx]);
}

// ---- LayerNorm over C=192; 4 rows/block, one wave per row
__global__ __launch_bounds__(256) void ln_kernel(const float* __restrict__ x,
    const float* __restrict__ w, const float* __restrict__ b,
    unsigned short* __restrict__ out) {
  int row  = blockIdx.x * 4 + (threadIdx.x >> 6);
  int lane = threadIdx.x & 63;
  const float* xr = x + (size_t)row * CD;
  float v0 = xr[lane], v1 = xr[lane + 64], v2 = xr[lane + 128];
  float s = v0 + v1 + v2;
  for (int o = 32; o; o >>= 1) s += __shfl_xor(s, o);
  float mu = s * (1.f / 192.f);
  float d0 = v0 - mu, d1 = v1 - mu, d2 = v2 - mu;
  float vv = d0 * d0 + d1 * d1 + d2 * d2;
  for (int o = 32; o; o >>= 1) vv += __shfl_xor(vv, o);
  float rstd = rsqrtf(vv * (1.f / 192.f) + 1e-5f);
  unsigned short* orow = out + (size_t)row * CD;
  orow[lane]       = f2b(d0 * rstd * w[lane]       + b[lane]);
  orow[lane + 64]  = f2b(d1 * rstd * w[lane + 64]  + b[lane + 64]);
  orow[lane + 128] = f2b(d2 * rstd * w[lane + 128] + b[lane + 128]);
}

// ---- bf16 MFMA GEMM: C[M,N] = A[M,K] * WT[N,K]^T (+bias, epilogue variants)
// EPI: 0 = bias -> bf16 ; 1 = bias + resid(f32) -> f32 ;
//      2 = bias + exact GELU -> bf16 ; 3 = bias, += into f32 out
template<int EPI>
__global__ __launch_bounds__(256) void gemm_kernel(
    const unsigned short* __restrict__ A,   // [M,K] bf16
    const unsigned short* __restrict__ WT,  // [N,K] bf16
    const float* __restrict__ bias,         // [N]
    void* __restrict__ outp,
    const float* __restrict__ resid,        // [M,N] for EPI==1
    int N, int K) {
  __shared__ __align__(16) unsigned short As[4][64][8];
  __shared__ __align__(16) unsigned short Bs[4][64][8];
  const int m0 = blockIdx.x * 64, n0 = blockIdx.y * 64;
  const int t = threadIdx.x;
  const int wave = t >> 6, lane = t & 63;
  const int lrow = lane & 15, lkg = lane >> 4;
  const int srow = t >> 2, skg = t & 3;   // staging: 16B per thread, coalesced
  const unsigned short* Ab = A  + (size_t)(m0 + srow) * K + skg * 8;
  const unsigned short* Bb = WT + (size_t)(n0 + srow) * K + skg * 8;
  f32x4 acc[4] = {};
  for (int k0 = 0; k0 < K; k0 += 32) {
    __syncthreads();
    *reinterpret_cast<int4*>(&As[skg][srow][0]) = *reinterpret_cast<const int4*>(Ab + k0);
    *reinterpret_cast<int4*>(&Bs[skg][srow][0]) = *reinterpret_cast<const int4*>(Bb + k0);
    __syncthreads();
    bf16x8 a = *reinterpret_cast<const bf16x8*>(&As[lkg][wave * 16 + lrow][0]);
#pragma unroll
    for (int nt = 0; nt < 4; ++nt) {
      bf16x8 bf = *reinterpret_cast<const bf16x8*>(&Bs[lkg][nt * 16 + lrow][0]);
      acc[nt] = __builtin_amdgcn_mfma_f32_16x16x32_bf16(a, bf, acc[nt], 0, 0, 0);
    }
  }
#pragma unroll
  for (int nt = 0; nt < 4; ++nt) {
    int n = n0 + nt * 16 + lrow;
    float bv = bias[n];
#pragma unroll
    for (int r = 0; r < 4; ++r) {
      int m = m0 + wave * 16 + lkg * 4 + r;
      float val = acc[nt][r] + bv;
      size_t oi = (size_t)m * N + n;
      if constexpr (EPI == 0) {
        ((unsigned short*)outp)[oi] = f2b(val);
      } else if constexpr (EPI == 1) {
        ((float*)outp)[oi] = val + resid[oi];
      } else if constexpr (EPI == 2) {
        val = 0.5f * val * (1.f + erff(val * 0.70710678118654752f));
        ((unsigned short*)outp)[oi] = f2b(val);
      } else {
        ((float*)outp)[oi] += val;
      }
    }
  }
}

// ---- MFMA windowed attention: 1 block = 1 window, 6 waves = 6 heads.
// St = K*Q^T (16x16x32 MFMA, K-dim=HD=32, frags straight from global);
// col-parallel softmax in St layout; P packed to LDS [q][ktok];
// O^T = V^T * P^T (V transposed into LDS at gather).
__global__ __launch_bounds__(384) void attn_kernel(
    const unsigned short* __restrict__ qkv,  // [M, 576] bf16 (3,NH,HD packing)
    const float* __restrict__ rpb,           // [169, 6]
    unsigned short* __restrict__ o) {        // [M, 192] bf16, natural token order
  constexpr int PIT = 68;                    // LDS row pitch (elems); 136B rows
  __shared__ unsigned short Vt[NHEAD][HD][PIT];   // [head][dim][ktok]
  __shared__ unsigned short Pl[NHEAD][64][PIT];   // [head][q][ktok]
  __shared__ int toks[64];
  const int bid = blockIdx.x;
  const int b = bid >> 6, w = bid & 63;
  const int wr = w >> 3, wc = w & 7;
  const int tid = threadIdx.x;
  // phase 1: window token table (wave 0), shared by all heads
  if (tid < 64) {
    int t = tid, tok;
    if (t < NT) {
      int ii = t / 7, jj = t - ii * 7;
      int hs = wr * 7 + ii, ws_ = wc * 7 + jj;           // shifted coords
      tok = b * 3136 + ((hs + 3) % 56) * 56 + ((ws_ + 3) % 56);
    } else tok = b * 3136;                               // safe pad row
    toks[t] = tok;
  }
  __syncthreads();
  const int h = tid >> 6, lane = tid & 63;
  const int g = lane >> 4, c = lane & 15;
  // --- V gather + transpose into LDS (lane = token; 2B writes are 2-way/free)
  {
    int row = toks[lane];
    const unsigned int* vr = (const unsigned int*)(qkv + (size_t)row * 576 + 384 + h * 32);
    unsigned int vv[16];
#pragma unroll
    for (int i = 0; i < 16; ++i) vv[i] = vr[i];
#pragma unroll
    for (int i = 0; i < 16; ++i) {
      Vt[h][2 * i][lane]     = (unsigned short)(vv[i] & 0xffffu);
      Vt[h][2 * i + 1][lane] = (unsigned short)(vv[i] >> 16);
    }
  }
  // --- K (A-frag) / Q (B-frag) direct from global; layout as verified GEMM
  int tokid[4];
#pragma unroll
  for (int mt = 0; mt < 4; ++mt) tokid[mt] = toks[mt * 16 + c];
  bf16x8 afr[4], bfr[4];
#pragma unroll
  for (int mt = 0; mt < 4; ++mt) {
    const unsigned short* base = qkv + (size_t)tokid[mt] * 576 + h * 32 + g * 8;
    bfr[mt] = *(const bf16x8*)(base);         // Q[tok][dim]  -> B[k=dim][n=qtok]
    afr[mt] = *(const bf16x8*)(base + 192);   // K[tok][dim]  -> A[m=ktok][k=dim]
  }
  // St[ktok][q]: tile (mt,nt); lane holds St[mt*16+g*4+r][nt*16+c]
  f32x4 acc[4][4] = {};
#pragma unroll
  for (int mt = 0; mt < 4; ++mt)
#pragma unroll
    for (int nt = 0; nt < 4; ++nt)
      acc[mt][nt] = __builtin_amdgcn_mfma_f32_16x16x32_bf16(afr[mt], bfr[nt], acc[mt][nt], 0, 0, 0);
  // --- softmax over ktok (per q column) ---
  int qh6[4], qw6[4], rq[4];
#pragma unroll
  for (int nt = 0; nt < 4; ++nt) {
    int q = nt * 16 + c; int qc = q < NT ? q : NT - 1;
    int yh = qc / 7, yw = qc - yh * 7;
    qh6[nt] = yh; qw6[nt] = yw;
    int hs = wr * 7 + yh, ws_ = wc * 7 + yw;
    rq[nt] = (hs < 49 ? 0 : (hs < 53 ? 1 : 2)) * 3 + (ws_ < 49 ? 0 : (ws_ < 53 ? 1 : 2));
  }
  int kh_[16], kw_[16], rk[16], kv[16];
#pragma unroll
  for (int i = 0; i < 16; ++i) {              // i = mt*4 + r -> ktok
    int kt = (i >> 2) * 16 + g * 4 + (i & 3);
    kv[i] = (kt < NT);
    int ktc = kv[i] ? kt : NT - 1;
    int yh = ktc / 7, yw = ktc - yh * 7;
    kh_[i] = yh; kw_[i] = yw;
    int hs = wr * 7 + yh, ws_ = wc * 7 + yw;
    rk[i] = (hs < 49 ? 0 : (hs < 53 ? 1 : 2)) * 3 + (ws_ < 49 ? 0 : (ws_ < 53 ? 1 : 2));
  }
#pragma unroll
  for (int mt = 0; mt < 4; ++mt)
#pragma unroll
    for (int r = 0; r < 4; ++r) {
      int i = mt * 4 + r;
#pragma unroll
      for (int nt = 0; nt < 4; ++nt) {
        float s;
        if (kv[i]) {
          int idx = ((qh6[nt] - kh_[i] + 6) * 13 + (qw6[nt] - kw_[i] + 6)) * NHEAD + h;
          s = acc[mt][nt][r] * QSCALE + rpb[idx];
          if (rk[i] != rq[nt]) s -= 100.f;
        } else s = -1e30f;
        acc[mt][nt][r] = s;
      }
    }
  float inv[4];
#pragma unroll
  for (int nt = 0; nt < 4; ++nt) {
    float m = -1e30f;
#pragma unroll
    for (int mt = 0; mt < 4; ++mt)
#pragma unroll
      for (int r = 0; r < 4; ++r) m = fmaxf(m, acc[mt][nt][r]);
    m = fmaxf(m, __shfl_xor(m, 16));
    m = fmaxf(m, __shfl_xor(m, 32));
    float s = 0.f;
#pragma unroll
    for (int mt = 0; mt < 4; ++mt)
#pragma unroll
      for (int r = 0; r < 4; ++r) {
        float e = __expf(acc[mt][nt][r] - m);
        acc[mt][nt][r] = e; s += e;
      }
    s += __shfl_xor(s, 16);
    s += __shfl_xor(s, 32);
    inv[nt] = 1.f / s;
  }
  // --- pack P (bf16) to LDS: P[q][ktok]; r-quad is ktok-consecutive -> b64
#pragma unroll
  for (int mt = 0; mt < 4; ++mt)
#pragma unroll
    for (int nt = 0; nt < 4; ++nt) {
      unsigned int lo = (unsigned int)f2b(acc[mt][nt][0] * inv[nt]) |
                        ((unsigned int)f2b(acc[mt][nt][1] * inv[nt]) << 16);
      unsigned int hi = (unsigned int)f2b(acc[mt][nt][2] * inv[nt]) |
                        ((unsigned int)f2b(acc[mt][nt][3] * inv[nt]) << 16);
      uint2 pv; pv.x = lo; pv.y = hi;
      *(uint2*)&Pl[h][nt * 16 + c][mt * 16 + g * 4] = pv;
    }
  // --- O^T = V^T * P^T : A-frag Vt rows, B-frag Pl rows (GEMM WT pattern)
  bf16x8 va[2][2];   // [dt][s]
#pragma unroll
  for (int dt = 0; dt < 2; ++dt)
#pragma unroll
    for (int s = 0; s < 2; ++s) {
      bf16x4 lo = *(const bf16x4*)&Vt[h][dt * 16 + c][s * 32 + g * 8];
      bf16x4 hi = *(const bf16x4*)&Vt[h][dt * 16 + c][s * 32 + g * 8 + 4];
      va[dt][s] = __builtin_shufflevector(lo, hi, 0, 1, 2, 3, 4, 5, 6, 7);
    }
  bf16x8 pb[2][4];   // [s][nt]
#pragma unroll
  for (int s = 0; s < 2; ++s)
#pragma unroll
    for (int nt = 0; nt < 4; ++nt) {
      bf16x4 lo = *(const bf16x4*)&Pl[h][nt * 16 + c][s * 32 + g * 8];
      bf16x4 hi = *(const bf16x4*)&Pl[h][nt * 16 + c][s * 32 + g * 8 + 4];
      pb[s][nt] = __builtin_shufflevector(lo, hi, 0, 1, 2, 3, 4, 5, 6, 7);
    }
  f32x4 oacc[2][4] = {};
#pragma unroll
  for (int dt = 0; dt < 2; ++dt)
#pragma unroll
    for (int nt = 0; nt < 4; ++nt)
#pragma unroll
      for (int s = 0; s < 2; ++s)
        oacc[dt][nt] = __builtin_amdgcn_mfma_f32_16x16x32_bf16(va[dt][s], pb[s][nt], oacc[dt][nt], 0, 0, 0);
  // oacc[dt][nt][r] = O[q = nt*16+c][d = dt*16 + g*4 + r]; d-quad contiguous
#pragma unroll
  for (int nt = 0; nt < 4; ++nt) {
    int q = nt * 16 + c;
    if (q < NT) {
      int row = toks[q];
      unsigned short* op = o + (size_t)row * CD + h * 32 + g * 4;
#pragma unroll
      for (int dt = 0; dt < 2; ++dt) {
        uint2 ov;
        ov.x = (unsigned int)f2b(oacc[dt][nt][0]) | ((unsigned int)f2b(oacc[dt][nt][1]) << 16);
        ov.y = (unsigned int)f2b(oacc[dt][nt][2]) | ((unsigned int)f2b(oacc[dt][nt][3]) << 16);
        *(uint2*)(op + dt * 16) = ov;
      }
    }
  }
}

extern "C" void kernel_launch(void* const* d_in, const int* in_sizes, int n_in,
                              void* d_out, int out_size, void* d_ws, size_t ws_size,
                              hipStream_t stream) {
  const float* x      = (const float*)d_in[0];
  const float* n1w    = (const float*)d_in[1];
  const float* n1b    = (const float*)d_in[2];
  const float* qkv_w  = (const float*)d_in[3];
  const float* qkv_b  = (const float*)d_in[4];
  const float* rpb    = (const float*)d_in[5];
  const float* proj_w = (const float*)d_in[6];
  const float* proj_b = (const float*)d_in[7];
  const float* n2w    = (const float*)d_in[8];
  const float* n2b    = (const float*)d_in[9];
  const float* fc1_w  = (const float*)d_in[10];
  const float* fc1_b  = (const float*)d_in[11];
  const float* fc2_w  = (const float*)d_in[12];
  const float* fc2_b  = (const float*)d_in[13];
  float* out = (float*)d_out;
  char* ws = (char*)d_ws;

  // workspace layout (bytes); hid aliases qkv+o (576+192=768 cols exactly)
  constexpr size_t SZ_HN  = (size_t)MTOK * CD  * 2;   // 77,070,336
  constexpr size_t SZ_QKV = (size_t)MTOK * 576 * 2;   // 231,211,008
  constexpr size_t OFF_QKV = SZ_HN;
  constexpr size_t OFF_O   = OFF_QKV + SZ_QKV;
  constexpr size_t OFF_WT  = OFF_O + SZ_HN;           // ~385.4 MB
  unsigned short* hnorm = (unsigned short*)(ws);            // LN1 out; reused for LN2
  unsigned short* qkvb  = (unsigned short*)(ws + OFF_QKV);
  unsigned short* obuf  = (unsigned short*)(ws + OFF_O);
  unsigned short* hid   = (unsigned short*)(ws + OFF_QKV);  // [M,768] aliases qkv+o
  unsigned short* qkv_wT  = (unsigned short*)(ws + OFF_WT); // [576,192]
  unsigned short* proj_wT = qkv_wT + 576 * 192;             // [192,192]
  unsigned short* fc1_wT  = proj_wT + 192 * 192;            // [768,192]
  unsigned short* fc2_wT  = fc1_wT + 768 * 192;             // [192,768]

  wtrans_kernel<<<(192 * 576 + 255) / 256, 256, 0, stream>>>(qkv_w, qkv_wT, 192, 576);
  wtrans_kernel<<<(192 * 192 + 255) / 256, 256, 0, stream>>>(proj_w, proj_wT, 192, 192);
  wtrans_kernel<<<(192 * 768 + 255) / 256, 256, 0, stream>>>(fc1_w, fc1_wT, 192, 768);
  wtrans_kernel<<<(768 * 192 + 255) / 256, 256, 0, stream>>>(fc2_w, fc2_wT, 768, 192);

  ln_kernel<<<MTOK / 4, 256, 0, stream>>>(x, n1w, n1b, hnorm);
  gemm_kernel<0><<<dim3(MTOK / 64, 9), 256, 0, stream>>>(hnorm, qkv_wT, qkv_b, qkvb, nullptr, 576, 192);
  attn_kernel<<<64 * 64, 384, 0, stream>>>(qkvb, rpb, obuf);
  gemm_kernel<1><<<dim3(MTOK / 64, 3), 256, 0, stream>>>(obuf, proj_wT, proj_b, out, x, 192, 192);
  ln_kernel<<<MTOK / 4, 256, 0, stream>>>(out, n2w, n2b, hnorm);
  gemm_kernel<2><<<dim3(MTOK / 64, 12), 256, 0, stream>>>(hnorm, fc1_wT, fc1_b, hid, nullptr, 768, 192);
  gemm_kernel<3><<<dim3(MTOK / 64, 3), 256, 0, stream>>>(hid, fc2_wT, fc2_b, out, nullptr, 192, 768);
}